// Round 17
// baseline (508.088 us; speedup 1.0000x reference)
//
#include <hip/hip_runtime.h>
#include <math.h>

#define NROWS 16384
#define NCOLS 16384
#define DIM   128
#define TM    64               // rows per block (4 waves x 16)
#define TN    64               // cols per chunk
#define NSPLIT 4
#define CPS   (NCOLS/NSPLIT)   // 4096 cols per split
#define NCH   (CPS/TN)         // 64 chunks
#define KP    16               // candidates per (row, split)

typedef __attribute__((ext_vector_type(8))) short bf16x8;
typedef __attribute__((ext_vector_type(4))) float f32x4;

__device__ __forceinline__ unsigned short bf16_rne(float x) {
  unsigned u = __float_as_uint(x);
  unsigned r = u + 0x7fffu + ((u >> 16) & 1u);
  return (unsigned short)(r >> 16);
}

// Monotone fp32->u32 order map, top 18 bits of value; low 14 bits hold
// (16383 - col) so ties prefer LOWER column in max-compare.
__device__ __forceinline__ unsigned mkkey(float v, int col) {
  unsigned b = __float_as_uint(v);
  unsigned u = b ^ (unsigned)(((int)b >> 31) | (int)0x80000000);
  return (u & 0xFFFFC000u) | (unsigned)(16383 - col);
}

// Branchless-shift insert: entry test, then max/min compare-exchange chain.
#define INSERT(tk, key) do {                                                  \
  unsigned _k = (key);                                                        \
  if (_k > tk[KP - 1]) {                                                      \
    tk[KP - 1] = _k;                                                          \
    _Pragma("unroll")                                                         \
    for (int _m = KP - 1; _m > 0; --_m) {                                     \
      unsigned _hi = tk[_m - 1] > tk[_m] ? tk[_m - 1] : tk[_m];               \
      unsigned _lo = tk[_m - 1] > tk[_m] ? tk[_m] : tk[_m - 1];               \
      tk[_m - 1] = _hi; tk[_m] = _lo;                                         \
    }                                                                         \
  }                                                                           \
} while (0)

// Barrier draining ONLY LDS ops; global loads/stores stay in flight.
#define BAR() do {                                   \
  __builtin_amdgcn_sched_barrier(0);                 \
  asm volatile("s_waitcnt lgkmcnt(0)" ::: "memory"); \
  __builtin_amdgcn_s_barrier();                      \
  __builtin_amdgcn_sched_barrier(0);                 \
} while (0)

// ---- kernel 0: hi-only bf16 MFMA fragment image of C (proven R9-R16) ----
// 256 chunks (64 cols) x 16KB. Tile T=cbk*4+ks (1KB), slot = T*1024 + ln*16,
// ln = (col&15) | ((k>>3)&3)<<4.
__global__ __launch_bounds__(256) void split_kernel(
    const float* __restrict__ C, unsigned char* __restrict__ Cimg)
{
  const unsigned u = blockIdx.x * 256 + threadIdx.x;  // 131072 threads
  const int c  = u & 16383;      // cluster id (S column)
  const int kk = u >> 14;        // 0..7: k-group of 16
  const f32x4* src = (const f32x4*)(C + (size_t)c * DIM + kk * 16);
  f32x4 f[4];
  f[0] = src[0]; f[1] = src[1]; f[2] = src[2]; f[3] = src[3];
  const unsigned chunkbase = ((unsigned)(c >> 6)) << 14;   // 16KB chunks
  const unsigned T = ((((unsigned)c >> 4) & 3u) << 2) | ((unsigned)kk >> 1);
  #pragma unroll
  for (int s = 0; s < 2; ++s) {
    bf16x8 h;
    #pragma unroll
    for (int e = 0; e < 8; ++e)
      h[e] = (short)bf16_rne(f[s * 2 + (e >> 2)][e & 3]);
    unsigned ln = (unsigned)(c & 15) | ((((unsigned)kk * 2 + s) & 3u) << 4);
    *(bf16x8*)&Cimg[chunkbase + (T << 10) + (ln << 4)] = h;
  }
}

// ---- kernel 1: fused hi-only GEMM + 4-chunk-grouped bounce -> 1KB-per-row
//      dump bursts + per-row top-16 candidate keys.
// 256 threads = 4 waves x 16 rows. LDS 80KB: B single 16KB + 4 x 16KB
// wave-private bounce -> 2 blocks/CU. Dump: 64 lanes x 16B = 1KB of ONE
// S row per instruction (DRAM page-locality lever).
__global__ __launch_bounds__(256, 2) void sim_topk_kernel(
    const float* __restrict__ Q, const unsigned char* __restrict__ Cimg,
    float* __restrict__ S, int* __restrict__ cand)
{
  __shared__ __align__(16) unsigned char lds[81920];
  const int t = threadIdx.x;
  const int w = t >> 6, lane = t & 63;

  // XCD-aware: 2 XCDs per col-split (1MB hi image resident per L2 pair)
  const int bid = blockIdx.x;              // 1024 blocks
  const int xcd = bid & 7;
  const int cs  = xcd >> 1;                       // 0..3
  const int rb  = ((xcd & 1) << 7) | (bid >> 3);  // 0..255
  const int row0 = rb * TM;
  const int col0 = cs * CPS;
  const int phase = (rb & 15) << 2;               // group-aligned stagger
  unsigned char* bounce = lds + 16384u + (unsigned)w * 16384u;

  // ---- A (query) hi fragments: wave owns rows [row0+16w,+16) ----
  const int arow = row0 + w * 16 + (lane & 15);
  bf16x8 a_h[4];
  {
    const f32x4* Qp = (const f32x4*)(Q + (size_t)arow * DIM) + (lane >> 4) * 2;
    #pragma unroll
    for (int ks = 0; ks < 4; ++ks) {
      f32x4 x0 = Qp[ks * 8], x1 = Qp[ks * 8 + 1];
      #pragma unroll
      for (int e = 0; e < 8; ++e)
        a_h[ks][e] = (short)bf16_rne((e < 4) ? x0[e & 3] : x1[e & 3]);
    }
  }

  // ---- staging: 16KB chunk = 256 threads x 64B (4 x f32x4), single buffer ----
  f32x4 st[4];
  auto gload = [&](int ch) {
    const f32x4* p = (const f32x4*)(Cimg + (((size_t)(cs * NCH + ch)) << 14)) + t;
    st[0] = p[0]; st[1] = p[256]; st[2] = p[512]; st[3] = p[768];
  };
  auto swrite = [&]() {
    #pragma unroll
    for (int r = 0; r < 4; ++r)
      *(f32x4*)&lds[(unsigned)r * 4096u + (unsigned)t * 16u] = st[r];
  };

  gload(phase);

  unsigned tk[KP];
  #pragma unroll
  for (int j = 0; j < KP; ++j) tk[j] = 0u;

  const int r16 = lane & 15;
  const unsigned rsw = (unsigned)(r16 & 7);

  for (int i = 0; i < NCH; ++i) {
    const int ch = (phase + i) & (NCH - 1);

    BAR();               // all waves done reading B of previous chunk
    swrite();            // stage chunk ch (st loaded last iteration)
    if (i + 1 < NCH) gload((phase + i + 1) & (NCH - 1));
    BAR();               // B staged for all waves

    // ---- MFMA: 4 independent col-tile chains x 4 ks ----
    f32x4 acc[4];
    #pragma unroll
    for (int c = 0; c < 4; ++c) acc[c] = {0.f, 0.f, 0.f, 0.f};
    #pragma unroll
    for (int ks = 0; ks < 4; ++ks) {
      #pragma unroll
      for (int ct = 0; ct < 4; ++ct) {
        unsigned o = ((unsigned)(ct * 4 + ks) << 10) + ((unsigned)lane << 4);
        bf16x8 bh = *(const bf16x8*)&lds[o];
        acc[ct] = __builtin_amdgcn_mfma_f32_16x16x32_bf16(bh, a_h[ks], acc[ct], 0, 0, 0);
      }
    }

    // ---- bounce write (wave-private, no sync) + top-k scan ----
    {
      const int colg0 = col0 + ch * TN;
      #pragma unroll
      for (int ct = 0; ct < 4; ++ct) {
        unsigned X = (unsigned)((ch & 3) * 16 + ct * 4 + (lane >> 4));
        *(f32x4*)&bounce[(unsigned)r16 * 1024u + ((X ^ rsw) << 4)] = acc[ct];
        const int cg = colg0 + ct * 16 + (lane >> 4) * 4;
        #pragma unroll
        for (int e = 0; e < 4; ++e)
          INSERT(tk, mkkey(acc[ct][e], cg + e));
      }
    }

    // ---- group dump: 16 instructions, each 1KB linear within ONE row ----
    if ((i & 3) == 3) {
      const int gbase = col0 + (ch & ~3) * TN;
      #pragma unroll
      for (int r = 0; r < 16; ++r) {
        f32x4 v = *(const f32x4*)&bounce[(unsigned)r * 1024u +
                      (((unsigned)(lane ^ (r & 7))) << 4)];
        *(f32x4*)&S[(size_t)(row0 + w * 16 + r) * NCOLS + gbase + lane * 4] = v;
      }
    }
  }

  // ---- merge 4 col-lanes per row (l, l^16, l^32, l^48) -> top-16/split ----
  #pragma unroll
  for (int off = 16; off <= 32; off <<= 1) {
    unsigned ov[KP];
    #pragma unroll
    for (int j = 0; j < KP; ++j)
      ov[j] = (unsigned)__shfl_xor((int)tk[j], off);
    #pragma unroll
    for (int j = 0; j < KP; ++j) INSERT(tk, ov[j]);
  }
  if (lane < 16) {
    int* dst = cand + ((size_t)(row0 + w * 16 + lane) * NSPLIT + cs) * KP;
    #pragma unroll
    for (int j = 0; j < KP; ++j) dst[j] = 16383 - (int)(tk[j] & 0x3FFFu);
  }
}

// ---- kernel 2: exact fp64 re-rank of 64 candidates/row -> ids + top-8 sims ----
__global__ __launch_bounds__(256) void rerank_kernel(
    const float* __restrict__ Q, const float* __restrict__ C,
    const int* __restrict__ cand, float* __restrict__ out)
{
  const int t = threadIdx.x, w = t >> 6, lane = t & 63;
  const int r = blockIdx.x * 4 + w;
  const f32x4* Q4 = (const f32x4*)(Q + (size_t)r * DIM);

  const int cidx = cand[(size_t)r * (NSPLIT * KP) + lane];  // 64 cands
  const f32x4* C4 = (const f32x4*)(C + (size_t)cidx * DIM);

  double acc = 0.0;
  #pragma unroll 8
  for (int d4 = 0; d4 < 32; ++d4) {
    f32x4 q = Q4[d4];
    f32x4 c = C4[d4];
    acc += (double)q[0] * (double)c[0];
    acc += (double)q[1] * (double)c[1];
    acc += (double)q[2] * (double)c[2];
    acc += (double)q[3] * (double)c[3];
  }

  double mv = acc;
  int    mi = cidx;

  float* oi = out;                           // ids as float32
  float* os = out + (size_t)NROWS * 8;       // top-8 sims

  for (int k = 0; k < 8; ++k) {
    double bv = mv; int bi = mi;
    #pragma unroll
    for (int off = 32; off >= 1; off >>= 1) {
      double ov = __shfl_xor(bv, off);
      int    o2 = __shfl_xor(bi, off);
      if (ov > bv || (ov == bv && o2 < bi)) { bv = ov; bi = o2; }
    }
    if (lane == 0) {
      os[(size_t)r * 8 + k] = (float)bv;
      oi[(size_t)r * 8 + k] = (bv >= 0.0) ? (float)bi : -1.0f;
    }
    if (mi == bi) mv = -1.0e300;   // candidate ids unique per row
  }
}

extern "C" void kernel_launch(void* const* d_in, const int* in_sizes, int n_in,
                              void* d_out, int out_size, void* d_ws, size_t ws_size,
                              hipStream_t stream) {
  const float* Q = (const float*)d_in[0];
  const float* C = (const float*)d_in[1];
  float* out = (float*)d_out;
  float* S   = out + (size_t)2 * NROWS * 8;              // all_similarities

  unsigned char* Cimg = (unsigned char*)d_ws;            // 4 MB hi fragment image
  int* cand = (int*)(Cimg + 4194304);                    // 4 MB: [16384][4][16]

  split_kernel<<<dim3(512), dim3(256), 0, stream>>>(C, Cimg);
  sim_topk_kernel<<<dim3((NROWS / TM) * NSPLIT), dim3(256), 0, stream>>>(Q, Cimg, S, cand);
  rerank_kernel<<<dim3(NROWS / 4), dim3(256), 0, stream>>>(Q, C, cand, out);
}

// Round 18
// 448.597 us; speedup vs baseline: 1.1326x; 1.1326x over previous
//
#include <hip/hip_runtime.h>
#include <math.h>

#define NROWS 16384
#define NCOLS 16384
#define DIM   128
#define KP    16               // per-lane candidate keys; merged -> top-16/row

typedef __attribute__((ext_vector_type(8))) short bf16x8;
typedef __attribute__((ext_vector_type(4))) float f32x4;

__device__ __forceinline__ unsigned short bf16_rne(float x) {
  unsigned u = __float_as_uint(x);
  unsigned r = u + 0x7fffu + ((u >> 16) & 1u);
  return (unsigned short)(r >> 16);
}

// Monotone fp32->u32 order map, top 18 bits of value; low 14 bits hold
// (16383 - col) so ties prefer LOWER column in max-compare.
__device__ __forceinline__ unsigned mkkey(float v, int col) {
  unsigned b = __float_as_uint(v);
  unsigned u = b ^ (unsigned)(((int)b >> 31) | (int)0x80000000);
  return (u & 0xFFFFC000u) | (unsigned)(16383 - col);
}

// Branchless-shift insert: entry test, then max/min compare-exchange chain.
#define INSERT(tk, key) do {                                                  \
  unsigned _k = (key);                                                        \
  if (_k > tk[KP - 1]) {                                                      \
    tk[KP - 1] = _k;                                                          \
    _Pragma("unroll")                                                         \
    for (int _m = KP - 1; _m > 0; --_m) {                                     \
      unsigned _hi = tk[_m - 1] > tk[_m] ? tk[_m - 1] : tk[_m];               \
      unsigned _lo = tk[_m - 1] > tk[_m] ? tk[_m] : tk[_m - 1];               \
      tk[_m - 1] = _hi; tk[_m] = _lo;                                         \
    }                                                                         \
  }                                                                           \
} while (0)

// ---- kernel 0: hi-only bf16 MFMA fragment image of C (proven R9-R17) ----
// 256 chunks (64 cols) x 16KB. Tile T=cbk*4+ks (1KB), slot = T*1024 + ln*16,
// ln = (col&15) | ((k>>3)&3)<<4.
__global__ __launch_bounds__(256) void split_kernel(
    const float* __restrict__ C, unsigned char* __restrict__ Cimg)
{
  const unsigned u = blockIdx.x * 256 + threadIdx.x;  // 131072 threads
  const int c  = u & 16383;      // cluster id (S column)
  const int kk = u >> 14;        // 0..7: k-group of 16
  const f32x4* src = (const f32x4*)(C + (size_t)c * DIM + kk * 16);
  f32x4 f[4];
  f[0] = src[0]; f[1] = src[1]; f[2] = src[2]; f[3] = src[3];
  const unsigned chunkbase = ((unsigned)(c >> 6)) << 14;   // 16KB chunks
  const unsigned T = ((((unsigned)c >> 4) & 3u) << 2) | ((unsigned)kk >> 1);
  #pragma unroll
  for (int s = 0; s < 2; ++s) {
    bf16x8 h;
    #pragma unroll
    for (int e = 0; e < 8; ++e)
      h[e] = (short)bf16_rne(f[s * 2 + (e >> 2)][e & 3]);
    unsigned ln = (unsigned)(c & 15) | ((((unsigned)kk * 2 + s) & 3u) << 4);
    *(bf16x8*)&Cimg[chunkbase + (T << 10) + (ln << 4)] = h;
  }
}

// Load one 32-col step's 8 B-fragments (st in [0,512) global).
#define GLOADB(dst, st) do {                                                  \
  const bf16x8* _bp = (const bf16x8*)(Cimg + ((size_t)((st) >> 1) << 14));    \
  _Pragma("unroll")                                                           \
  for (int _i = 0; _i < 8; ++_i)                                              \
    dst[_i] = _bp[((((st) & 1) * 2 + (_i >> 2)) * 4 + (_i & 3)) * 64 + lane]; \
} while (0)

// Compute one 32-col step: 8 MFMA, 2 nontemporal f32x4 stores, topk scan.
#define STEP(bsrc, st) do {                                                   \
  f32x4 _a0 = {0.f, 0.f, 0.f, 0.f};                                           \
  f32x4 _a1 = {0.f, 0.f, 0.f, 0.f};                                           \
  _Pragma("unroll")                                                           \
  for (int _ks = 0; _ks < 4; ++_ks) {                                         \
    _a0 = __builtin_amdgcn_mfma_f32_16x16x32_bf16(bsrc[_ks],     a_h[_ks], _a0, 0, 0, 0); \
    _a1 = __builtin_amdgcn_mfma_f32_16x16x32_bf16(bsrc[4 + _ks], a_h[_ks], _a1, 0, 0, 0); \
  }                                                                           \
  const int _c0 = (st) * 32 + (lane >> 4) * 4;                                \
  float* _sp = Srow + _c0;                                                    \
  __builtin_nontemporal_store(_a0, (f32x4*)_sp);                              \
  __builtin_nontemporal_store(_a1, (f32x4*)(_sp + 16));                       \
  _Pragma("unroll")                                                           \
  for (int _e = 0; _e < 4; ++_e) {                                            \
    INSERT(tk, mkkey(_a0[_e], _c0 + _e));                                     \
    INSERT(tk, mkkey(_a1[_e], _c0 + 16 + _e));                                \
  }                                                                           \
} while (0)

// ---- kernel 1: contiguous-region fused GEMM. Block = 16 FULL rows = one
// private contiguous 1MB span of S. 4 waves x col-quarters, zero LDS, zero
// barriers; B ping-ponged in statically-indexed registers from L2 image. ----
__global__ __launch_bounds__(256, 4) void sim_topk_kernel(
    const float* __restrict__ Q, const unsigned char* __restrict__ Cimg,
    float* __restrict__ S, int* __restrict__ cand)
{
  const int t = threadIdx.x;
  const int w = t >> 6, lane = t & 63;
  const int bid = blockIdx.x;              // 1024 blocks
  const int row0 = bid * 16;               // block's 16 rows (contiguous 1MB)
  const int arow = row0 + (lane & 15);
  const int p0 = bid & 127;                // block-level step phase

  // ---- A (query) hi fragments for this wave's 16 rows ----
  bf16x8 a_h[4];
  {
    const f32x4* Qp = (const f32x4*)(Q + (size_t)arow * DIM) + (lane >> 4) * 2;
    #pragma unroll
    for (int ks = 0; ks < 4; ++ks) {
      f32x4 x0 = Qp[ks * 8], x1 = Qp[ks * 8 + 1];
      #pragma unroll
      for (int e = 0; e < 8; ++e)
        a_h[ks][e] = (short)bf16_rne((e < 4) ? x0[e & 3] : x1[e & 3]);
    }
  }

  float* Srow = S + (size_t)arow * NCOLS;
  unsigned tk[KP];
  #pragma unroll
  for (int j = 0; j < KP; ++j) tk[j] = 0u;

  // wave w owns steps [w*128, w*128+128) = cols [w*4096, +4096)
  const int sb = w * 128;
  bf16x8 bA[8], bB[8];
  GLOADB(bA, sb + p0);

  for (int m = 0; m < 64; ++m) {
    const int s0 = sb + ((p0 + 2 * m)     & 127);
    const int s1 = sb + ((p0 + 2 * m + 1) & 127);
    const int s2 = sb + ((p0 + 2 * m + 2) & 127);
    GLOADB(bB, s1);
    STEP(bA, s0);
    GLOADB(bA, s2);     // wraps to first step at m=63 (harmless re-load)
    STEP(bB, s1);
  }

  // ---- merge 4 col-lanes per row (l, l^16, l^32, l^48) -> top-16/row ----
  #pragma unroll
  for (int off = 16; off <= 32; off <<= 1) {
    unsigned ov[KP];
    #pragma unroll
    for (int j = 0; j < KP; ++j)
      ov[j] = (unsigned)__shfl_xor((int)tk[j], off);
    #pragma unroll
    for (int j = 0; j < KP; ++j) INSERT(tk, ov[j]);
  }
  if (t < 16) {   // one writer per row (wave 0's low lanes)
    int* dst = cand + (size_t)(row0 + t) * KP;
    #pragma unroll
    for (int j = 0; j < KP; ++j) dst[j] = 16383 - (int)(tk[j] & 0x3FFFu);
  } else if (lane < 16 && w > 0) {
    // other waves' lanes also hold merged lists for the same rows but over
    // DIFFERENT col quarters -- must be combined. Write per-wave lists.
    int* dst = cand + ((size_t)NROWS + (size_t)(w - 1) * NROWS + row0 + lane) * KP;
    #pragma unroll
    for (int j = 0; j < KP; ++j) dst[j] = 16383 - (int)(tk[j] & 0x3FFFu);
  }
}

// ---- kernel 2: exact fp64 re-rank of 64 candidates/row (4 waves' lists)
//      -> ids + top-8 sims ----
__global__ __launch_bounds__(256) void rerank_kernel(
    const float* __restrict__ Q, const float* __restrict__ C,
    const int* __restrict__ cand, float* __restrict__ out)
{
  const int t = threadIdx.x, w = t >> 6, lane = t & 63;
  const int r = blockIdx.x * 4 + w;
  const f32x4* Q4 = (const f32x4*)(Q + (size_t)r * DIM);

  // 64 candidates: wave list li = lane>>4 (0..3), slot j = lane&15
  const int li = lane >> 4;
  const size_t base = (li == 0) ? ((size_t)r * KP)
                                : (((size_t)NROWS + (size_t)(li - 1) * NROWS + r) * KP);
  const int cidx = cand[base + (lane & 15)];
  const f32x4* C4 = (const f32x4*)(C + (size_t)cidx * DIM);

  double acc = 0.0;
  #pragma unroll 8
  for (int d4 = 0; d4 < 32; ++d4) {
    f32x4 q = Q4[d4];
    f32x4 c = C4[d4];
    acc += (double)q[0] * (double)c[0];
    acc += (double)q[1] * (double)c[1];
    acc += (double)q[2] * (double)c[2];
    acc += (double)q[3] * (double)c[3];
  }

  double mv = acc;
  int    mi = cidx;

  float* oi = out;                           // ids as float32
  float* os = out + (size_t)NROWS * 8;       // top-8 sims

  for (int k = 0; k < 8; ++k) {
    double bv = mv; int bi = mi;
    #pragma unroll
    for (int off = 32; off >= 1; off >>= 1) {
      double ov = __shfl_xor(bv, off);
      int    o2 = __shfl_xor(bi, off);
      if (ov > bv || (ov == bv && o2 < bi)) { bv = ov; bi = o2; }
    }
    if (lane == 0) {
      os[(size_t)r * 8 + k] = (float)bv;
      oi[(size_t)r * 8 + k] = (bv >= 0.0) ? (float)bi : -1.0f;
    }
    if (mi == bi) mv = -1.0e300;   // duplicates across lists resolved by
                                   // (value,idx) tie-break; same idx can
                                   // appear in ONE list only (disjoint quarters)
  }
}

extern "C" void kernel_launch(void* const* d_in, const int* in_sizes, int n_in,
                              void* d_out, int out_size, void* d_ws, size_t ws_size,
                              hipStream_t stream) {
  const float* Q = (const float*)d_in[0];
  const float* C = (const float*)d_in[1];
  float* out = (float*)d_out;
  float* S   = out + (size_t)2 * NROWS * 8;              // all_similarities

  unsigned char* Cimg = (unsigned char*)d_ws;            // 4 MB hi fragment image
  int* cand = (int*)(Cimg + 4194304);                    // 4 MB: 4 lists x [16384][16]

  split_kernel<<<dim3(512), dim3(256), 0, stream>>>(C, Cimg);
  sim_topk_kernel<<<dim3(NROWS / 16), dim3(256), 0, stream>>>(Q, Cimg, S, cand);
  rerank_kernel<<<dim3(NROWS / 4), dim3(256), 0, stream>>>(Q, C, cand, out);
}